// Round 3
// baseline (5985.354 us; speedup 1.0000x reference)
//
#include <hip/hip_runtime.h>

#define T_  512
#define B_  128
#define D_  512
#define H_  512
#define N4H 2048
#define NB  64          // scan blocks; each owns 8 h-columns

typedef _Float16 half8  __attribute__((ext_vector_type(8)));
typedef _Float16 half4v __attribute__((ext_vector_type(4)));
typedef float    f32x4  __attribute__((ext_vector_type(4)));

// ---------- converts ----------
__global__ void cvt_ins(const float* __restrict__ in, _Float16* __restrict__ out) {
    int i = blockIdx.x * 256 + threadIdx.x;
    float4 v = ((const float4*)in)[i];
    half4v o;
    o[0] = (_Float16)v.x; o[1] = (_Float16)v.y;
    o[2] = (_Float16)v.z; o[3] = (_Float16)v.w;
    ((half4v*)out)[i] = o;
}

__global__ void cvt_wi(const float* __restrict__ Wi, _Float16* __restrict__ WiT) {
    int i = blockIdx.x * 256 + threadIdx.x;            // over 512*2048
    int k = i >> 11, n = i & 2047;
    WiT[n * D_ + k] = (_Float16)Wi[i];                 // transpose: [N][K]
}

// Pack Wh into per-scan-block LDS-ready layout:
// WhP2[n][ (nt*16+ks)*512 + (kc*16+col)*8 + e ] = Wh[k][gcol]
//   k = ks*32 + kc*8 + e ; sc = nt*16+col ; g = sc>>3 ; jj = sc&7 ; gcol = g*512 + n*8 + jj
__global__ void cvt_wh2(const float* __restrict__ Wh, _Float16* __restrict__ WhP2) {
    int i = blockIdx.x * 256 + threadIdx.x;            // over 512*2048 (coalesced src)
    int k = i >> 11, gcol = i & 2047;
    int g = gcol >> 9, j = gcol & 511;
    int n = j >> 3, jj = j & 7;
    int sc = g * 8 + jj;
    int nt = sc >> 4, col = sc & 15;
    int ks = k >> 5, kc = (k >> 3) & 3, e = k & 7;
    int idx = (nt * 16 + ks) * 512 + (kc * 16 + col) * 8 + e;
    WhP2[(size_t)n * 16384 + idx] = (_Float16)Wh[i];
}

// hbuf[0] = resets[0]-masked h0 (f16); also zero the barrier counter
__global__ void init_h(const float* __restrict__ h0, const int* __restrict__ resets,
                       _Float16* __restrict__ hbuf, int* __restrict__ bar) {
    int i = blockIdx.x * 512 + threadIdx.x;            // over B*H
    int b = i >> 9;
    hbuf[i] = (_Float16)(resets[b] ? 0.f : h0[i]);
    if (i == 0) *bar = 0;
}

// ---------- phase 1: Z = X @ WiT^T, written PERMUTED per scan block ----------
// Zp[t][n][b][sc]  (sc = g*8+jj), so the scan reads 8KB contiguous per step.
__global__ __launch_bounds__(256) void gemm_xwi(const _Float16* __restrict__ X,
                                                const _Float16* __restrict__ WT,
                                                _Float16* __restrict__ Zp) {
    __shared__ _Float16 As[128 * 32];
    __shared__ _Float16 Bs[128 * 32];
    const int tid  = threadIdx.x;
    const int lane = tid & 63;
    const int wid  = tid >> 6;
    const int wm   = wid >> 1, wn = wid & 1;
    const int bm   = blockIdx.x, bn = blockIdx.y;

    f32x4 acc[4][4];
    #pragma unroll
    for (int m = 0; m < 4; ++m)
        #pragma unroll
        for (int n = 0; n < 4; ++n)
            acc[m][n] = (f32x4){0.f, 0.f, 0.f, 0.f};

    const _Float16* Xb = X  + (size_t)bm * 128 * D_;
    const _Float16* Wb = WT + (size_t)bn * 128 * D_;

    for (int kt = 0; kt < D_ / 32; ++kt) {
        if (kt) __syncthreads();
        #pragma unroll
        for (int s = 0; s < 2; ++s) {
            int idx = tid + s * 256;
            int row = idx >> 2, cg = idx & 3;
            *(half8*)&As[idx * 8] = *(const half8*)&Xb[row * D_ + kt * 32 + cg * 8];
            *(half8*)&Bs[idx * 8] = *(const half8*)&Wb[row * D_ + kt * 32 + cg * 8];
        }
        __syncthreads();
        half8 a[4], b[4];
        #pragma unroll
        for (int m = 0; m < 4; ++m)
            a[m] = *(const half8*)&As[(wm * 64 + m * 16 + (lane & 15)) * 32 + (lane >> 4) * 8];
        #pragma unroll
        for (int n = 0; n < 4; ++n)
            b[n] = *(const half8*)&Bs[(wn * 64 + n * 16 + (lane & 15)) * 32 + (lane >> 4) * 8];
        #pragma unroll
        for (int m = 0; m < 4; ++m)
            #pragma unroll
            for (int n = 0; n < 4; ++n)
                acc[m][n] = __builtin_amdgcn_mfma_f32_16x16x32_f16(a[m], b[n], acc[m][n], 0, 0, 0);
    }

    const int row0 = bm * 128 + wm * 64;
    const int col0 = bn * 128 + wn * 64;
    #pragma unroll
    for (int m = 0; m < 4; ++m)
        #pragma unroll
        for (int n = 0; n < 4; ++n)
            #pragma unroll
            for (int e = 0; e < 4; ++e) {
                int r = row0 + m * 16 + (lane >> 4) * 4 + e;   // t*B + b
                int c = col0 + n * 16 + (lane & 15);           // gate col
                int t = r >> 7, bb = r & 127;
                int g = c >> 9, j = c & 511;
                int nb = j >> 3, jj = j & 7;
                Zp[(((size_t)t * NB + nb) * 128 + bb) * 32 + g * 8 + jj] = (_Float16)acc[m][n][e];
            }
}

// ---------- phase 2: persistent cooperative scan ----------
__global__ __launch_bounds__(512) void lstm_scan2(const _Float16* __restrict__ Zp,
                                                  const _Float16* __restrict__ WhP2,
                                                  const float* __restrict__ bv,
                                                  const int* __restrict__ resets,
                                                  const float* __restrict__ c0,
                                                  _Float16* __restrict__ hbuf,  // [2][B][H]
                                                  int* __restrict__ bar,
                                                  float* __restrict__ out) {
    const int n    = blockIdx.x;
    const int tid  = threadIdx.x;
    const int lane = tid & 63;
    const int w    = tid >> 6;                 // wave id = m-tile (16 batch rows)
    const int jbase = n * 8;

    __shared__ _Float16 WL[16384];             // 32KB weight slice
    __shared__ float    zl[128 * 33];          // z exchange, padded rows

    {   // weights: one-time linear copy to LDS
        const half8* src = (const half8*)(WhP2 + (size_t)n * 16384);
        half8* dst = (half8*)WL;
        for (int i = tid; i < 2048; i += 512) dst[i] = src[i];
    }

    const int b   = tid >> 2;                  // batch row this thread finalizes
    const int q   = tid & 3;
    const int jj0 = q * 2;                     // handles jj0, jj0+1

    float bia[4][2];
    #pragma unroll
    for (int g = 0; g < 4; ++g) {
        bia[g][0] = bv[g * 512 + jbase + jj0];
        bia[g][1] = bv[g * 512 + jbase + jj0 + 1];
    }

    float cc0 = c0[b * 512 + jbase + jj0];
    float cc1 = c0[b * 512 + jbase + jj0 + 1];
    float hh0 = 0.f, hh1 = 0.f;

    float* ys = out + 2 * (B_ * H_);

    const int arow = w * 16 + (lane & 15);
    const int koff = (lane >> 4) * 8;
    const int boff = ((lane >> 4) * 16 + (lane & 15)) * 8;

    __syncthreads();                           // WL ready

    for (int t = 0; t < T_; ++t) {
        const _Float16* hsrc = hbuf + (size_t)(t & 1) * (B_ * H_);
        const _Float16* aptr = hsrc + arow * 512 + koff;

        half8 av[16];
        #pragma unroll
        for (int ks = 0; ks < 16; ++ks) av[ks] = *(const half8*)(aptr + ks * 32);

        f32x4 acc0 = (f32x4){0.f,0.f,0.f,0.f}, acc1 = (f32x4){0.f,0.f,0.f,0.f};
        #pragma unroll
        for (int ks = 0; ks < 16; ++ks) {
            half8 b0 = *(const half8*)&WL[ks * 512 + boff];
            half8 b1 = *(const half8*)&WL[(16 + ks) * 512 + boff];
            acc0 = __builtin_amdgcn_mfma_f32_16x16x32_f16(av[ks], b0, acc0, 0, 0, 0);
            acc1 = __builtin_amdgcn_mfma_f32_16x16x32_f16(av[ks], b1, acc1, 0, 0, 0);
        }

        {   // scatter z to LDS (row-padded: conflict-free)
            const int r0 = w * 16 + (lane >> 4) * 4;
            const int cl = lane & 15;
            #pragma unroll
            for (int e = 0; e < 4; ++e) {
                zl[(r0 + e) * 33 + cl]      = acc0[e];
                zl[(r0 + e) * 33 + 16 + cl] = acc1[e];
            }
        }
        __syncthreads();

        // epilogue: gates for (b, jj0), (b, jj0+1)
        const int  rb  = resets[t * B_ + b];
        const float cm0 = rb ? 0.f : cc0;
        const float cm1 = rb ? 0.f : cc1;
        const _Float16* zp = Zp + (((size_t)t * NB + n) * 128 + b) * 32;
        float zt[4][2];
        #pragma unroll
        for (int g = 0; g < 4; ++g) {
            zt[g][0] = zl[b * 33 + g * 8 + jj0]     + bia[g][0] + (float)zp[g * 8 + jj0];
            zt[g][1] = zl[b * 33 + g * 8 + jj0 + 1] + bia[g][1] + (float)zp[g * 8 + jj0 + 1];
        }
        {
            float ig = 1.f / (1.f + __expf(-zt[0][0]));
            float fg = 1.f / (1.f + __expf(-zt[1][0]));
            float gg = 1.f - 2.f / (1.f + __expf(2.f * zt[2][0]));
            float og = 1.f / (1.f + __expf(-zt[3][0]));
            cc0 = fg * cm0 + ig * gg;
            hh0 = og * (1.f - 2.f / (1.f + __expf(2.f * cc0)));
        }
        {
            float ig = 1.f / (1.f + __expf(-zt[0][1]));
            float fg = 1.f / (1.f + __expf(-zt[1][1]));
            float gg = 1.f - 2.f / (1.f + __expf(2.f * zt[2][1]));
            float og = 1.f / (1.f + __expf(-zt[3][1]));
            cc1 = fg * cm1 + ig * gg;
            hh1 = og * (1.f - 2.f / (1.f + __expf(2.f * cc1)));
        }

        *(float2*)&ys[(size_t)(t * B_ + b) * H_ + jbase + jj0] = (float2){hh0, hh1};

        const int rn = (t + 1 < T_) ? resets[(t + 1) * B_ + b] : 0;
        union { unsigned int u; _Float16 h[2]; } hp;
        hp.h[0] = (_Float16)(rn ? 0.f : hh0);
        hp.h[1] = (_Float16)(rn ? 0.f : hh1);
        *(unsigned int*)(hbuf + (size_t)((t + 1) & 1) * (B_ * H_) + b * 512 + jbase + jj0) = hp.u;

        __syncthreads();                       // all stores issued+drained (vmcnt0 at barrier)
        if (tid == 0) {
            __threadfence();                   // agent release: L2 writeback for cross-XCD
            __hip_atomic_fetch_add(bar, 1, __ATOMIC_RELEASE, __HIP_MEMORY_SCOPE_AGENT);
            const int target = NB * (t + 1);
            while (__hip_atomic_load(bar, __ATOMIC_ACQUIRE, __HIP_MEMORY_SCOPE_AGENT) < target)
                __builtin_amdgcn_s_sleep(2);   // acquire load: invalidates L1/L2
        }
        __syncthreads();                       // release whole block; h_{t+1} visible
    }

    // final outputs: c_T and raw h_T
    *(float2*)&out[b * 512 + jbase + jj0]            = (float2){cc0, cc1};
    *(float2*)&out[B_ * H_ + b * 512 + jbase + jj0]  = (float2){hh0, hh1};
}

// ---------- fallback: all-f32 fused (used only if workspace too small) ----------
__global__ __launch_bounds__(512) void lstm_fb(const float* __restrict__ ins,
                                               const int* __restrict__ resets,
                                               const float* __restrict__ c0,
                                               const float* __restrict__ h0,
                                               const float* __restrict__ Wi,
                                               const float* __restrict__ Wh,
                                               const float* __restrict__ bv,
                                               float* __restrict__ out) {
    const int b = blockIdx.x;
    const int j = threadIdx.x;
    __shared__ float hs[H_];
    __shared__ float xs[D_];

    float c = c0[b * H_ + j];
    hs[j] = h0[b * H_ + j];
    const float b0 = bv[j], b1 = bv[H_ + j], b2 = bv[2 * H_ + j], b3 = bv[3 * H_ + j];
    float* ys = out + 2 * B_ * H_;

    for (int t = 0; t < T_; ++t) {
        __syncthreads();
        xs[j] = ins[((size_t)(t * B_ + b)) * D_ + j];
        __syncthreads();
        const bool rst = resets[t * B_ + b] != 0;
        float z0 = b0, z1 = b1, z2 = b2, z3 = b3;
        for (int k = 0; k < D_; ++k) {
            float xk = xs[k];
            z0 += xk * Wi[(size_t)k * N4H + j];
            z1 += xk * Wi[(size_t)k * N4H + H_ + j];
            z2 += xk * Wi[(size_t)k * N4H + 2 * H_ + j];
            z3 += xk * Wi[(size_t)k * N4H + 3 * H_ + j];
        }
        float c_use = rst ? 0.f : c;
        if (!rst) {
            for (int k = 0; k < H_; ++k) {
                float hk = hs[k];
                z0 += hk * Wh[(size_t)k * N4H + j];
                z1 += hk * Wh[(size_t)k * N4H + H_ + j];
                z2 += hk * Wh[(size_t)k * N4H + 2 * H_ + j];
                z3 += hk * Wh[(size_t)k * N4H + 3 * H_ + j];
            }
        }
        float ig = 1.f / (1.f + __expf(-z0));
        float fg = 1.f / (1.f + __expf(-z1));
        float gg = 1.f - 2.f / (1.f + __expf(2.f * z2));
        float og = 1.f / (1.f + __expf(-z3));
        c = fg * c_use + ig * gg;
        float tc = 1.f - 2.f / (1.f + __expf(2.f * c));
        float h = og * tc;
        __syncthreads();
        hs[j] = h;
        ys[((size_t)(t * B_ + b)) * H_ + j] = h;
    }
    out[b * H_ + j] = c;
    out[B_ * H_ + b * H_ + j] = hs[j];
}

extern "C" void kernel_launch(void* const* d_in, const int* in_sizes, int n_in,
                              void* d_out, int out_size, void* d_ws, size_t ws_size,
                              hipStream_t stream) {
    const float* ins    = (const float*)d_in[0];
    const int*   resets = (const int*)d_in[1];
    const float* c0     = (const float*)d_in[2];
    const float* h0     = (const float*)d_in[3];
    const float* Wi     = (const float*)d_in[4];
    const float* Wh     = (const float*)d_in[5];
    const float* bv     = (const float*)d_in[6];
    float*       out    = (float*)d_out;

    const size_t offXH  = 0;                                   // ins f16 (64MB); reused later
    const size_t offWiT = offXH  + (size_t)T_ * B_ * D_ * 2;
    const size_t offWhP = offWiT + (size_t)D_ * N4H * 2;
    const size_t offZ   = offWhP + (size_t)H_ * N4H * 2;
    const size_t need   = offZ   + (size_t)T_ * B_ * N4H * 2;

    if (ws_size >= need) {
        _Float16* XH   = (_Float16*)((char*)d_ws + offXH);
        _Float16* WiT  = (_Float16*)((char*)d_ws + offWiT);
        _Float16* WhP2 = (_Float16*)((char*)d_ws + offWhP);
        _Float16* Zp   = (_Float16*)((char*)d_ws + offZ);
        // hbuf + bar reuse the XH region (XH fully consumed by gemm before init_h)
        _Float16* hbuf = (_Float16*)((char*)d_ws + offXH);               // 2*B*H f16 = 256KB
        int*      bar  = (int*)((char*)d_ws + offXH + 2 * B_ * H_ * 2);

        cvt_ins<<<(T_ * B_ * D_ / 4) / 256, 256, 0, stream>>>(ins, XH);
        cvt_wi <<<(D_ * N4H) / 256,         256, 0, stream>>>(Wi, WiT);
        cvt_wh2<<<(H_ * N4H) / 256,         256, 0, stream>>>(Wh, WhP2);
        gemm_xwi<<<dim3(T_ * B_ / 128, N4H / 128), 256, 0, stream>>>(XH, WiT, Zp);
        init_h<<<B_ * H_ / 512, 512, 0, stream>>>(h0, resets, hbuf, bar);
        lstm_scan2<<<NB, 512, 0, stream>>>(Zp, WhP2, bv, resets, c0, hbuf, bar, out);
    } else {
        lstm_fb<<<B_, H_, 0, stream>>>(ins, resets, c0, h0, Wi, Wh, bv, out);
    }
}

// Round 4
// 5817.283 us; speedup vs baseline: 1.0289x; 1.0289x over previous
//
#include <hip/hip_runtime.h>

#define T_  512
#define B_  128
#define D_  512
#define H_  512
#define N4H 2048
#define NB  64          // scan blocks; each owns 8 h-columns

typedef _Float16 half8  __attribute__((ext_vector_type(8)));
typedef _Float16 half4v __attribute__((ext_vector_type(4)));
typedef float    f32x4  __attribute__((ext_vector_type(4)));

// ---------- converts ----------
__global__ void cvt_ins(const float* __restrict__ in, _Float16* __restrict__ out) {
    int i = blockIdx.x * 256 + threadIdx.x;
    float4 v = ((const float4*)in)[i];
    half4v o;
    o[0] = (_Float16)v.x; o[1] = (_Float16)v.y;
    o[2] = (_Float16)v.z; o[3] = (_Float16)v.w;
    ((half4v*)out)[i] = o;
}

__global__ void cvt_wi(const float* __restrict__ Wi, _Float16* __restrict__ WiT) {
    int i = blockIdx.x * 256 + threadIdx.x;            // over 512*2048
    int k = i >> 11, n = i & 2047;
    WiT[n * D_ + k] = (_Float16)Wi[i];                 // transpose: [N][K]
}

// Pack Wh into per-scan-block LDS-ready layout (see R3 notes).
__global__ void cvt_wh2(const float* __restrict__ Wh, _Float16* __restrict__ WhP2) {
    int i = blockIdx.x * 256 + threadIdx.x;            // over 512*2048 (coalesced src)
    int k = i >> 11, gcol = i & 2047;
    int g = gcol >> 9, j = gcol & 511;
    int n = j >> 3, jj = j & 7;
    int sc = g * 8 + jj;
    int nt = sc >> 4, col = sc & 15;
    int ks = k >> 5, kc = (k >> 3) & 3, e = k & 7;
    int idx = (nt * 16 + ks) * 512 + (kc * 16 + col) * 8 + e;
    WhP2[(size_t)n * 16384 + idx] = (_Float16)Wh[i];
}

// hbuf[0] = resets[0]-masked h0 (f16); also zero the barrier counter
__global__ void init_h(const float* __restrict__ h0, const int* __restrict__ resets,
                       _Float16* __restrict__ hbuf, int* __restrict__ bar) {
    int i = blockIdx.x * 512 + threadIdx.x;            // over B*H
    int b = i >> 9;
    hbuf[i] = (_Float16)(resets[b] ? 0.f : h0[i]);
    if (i == 0) *bar = 0;
}

// ---------- phase 1: Z = X @ WiT^T, written PERMUTED per scan block ----------
__global__ __launch_bounds__(256) void gemm_xwi(const _Float16* __restrict__ X,
                                                const _Float16* __restrict__ WT,
                                                _Float16* __restrict__ Zp) {
    __shared__ _Float16 As[128 * 32];
    __shared__ _Float16 Bs[128 * 32];
    const int tid  = threadIdx.x;
    const int lane = tid & 63;
    const int wid  = tid >> 6;
    const int wm   = wid >> 1, wn = wid & 1;
    const int bm   = blockIdx.x, bn = blockIdx.y;

    f32x4 acc[4][4];
    #pragma unroll
    for (int m = 0; m < 4; ++m)
        #pragma unroll
        for (int n = 0; n < 4; ++n)
            acc[m][n] = (f32x4){0.f, 0.f, 0.f, 0.f};

    const _Float16* Xb = X  + (size_t)bm * 128 * D_;
    const _Float16* Wb = WT + (size_t)bn * 128 * D_;

    for (int kt = 0; kt < D_ / 32; ++kt) {
        if (kt) __syncthreads();
        #pragma unroll
        for (int s = 0; s < 2; ++s) {
            int idx = tid + s * 256;
            int row = idx >> 2, cg = idx & 3;
            *(half8*)&As[idx * 8] = *(const half8*)&Xb[row * D_ + kt * 32 + cg * 8];
            *(half8*)&Bs[idx * 8] = *(const half8*)&Wb[row * D_ + kt * 32 + cg * 8];
        }
        __syncthreads();
        half8 a[4], b[4];
        #pragma unroll
        for (int m = 0; m < 4; ++m)
            a[m] = *(const half8*)&As[(wm * 64 + m * 16 + (lane & 15)) * 32 + (lane >> 4) * 8];
        #pragma unroll
        for (int n = 0; n < 4; ++n)
            b[n] = *(const half8*)&Bs[(wn * 64 + n * 16 + (lane & 15)) * 32 + (lane >> 4) * 8];
        #pragma unroll
        for (int m = 0; m < 4; ++m)
            #pragma unroll
            for (int n = 0; n < 4; ++n)
                acc[m][n] = __builtin_amdgcn_mfma_f32_16x16x32_f16(a[m], b[n], acc[m][n], 0, 0, 0);
    }

    const int row0 = bm * 128 + wm * 64;
    const int col0 = bn * 128 + wn * 64;
    #pragma unroll
    for (int m = 0; m < 4; ++m)
        #pragma unroll
        for (int n = 0; n < 4; ++n)
            #pragma unroll
            for (int e = 0; e < 4; ++e) {
                int r = row0 + m * 16 + (lane >> 4) * 4 + e;   // t*B + b
                int c = col0 + n * 16 + (lane & 15);           // gate col
                int t = r >> 7, bb = r & 127;
                int g = c >> 9, j = c & 511;
                int nb = j >> 3, jj = j & 7;
                Zp[(((size_t)t * NB + nb) * 128 + bb) * 32 + g * 8 + jj] = (_Float16)acc[m][n][e];
            }
}

// ---------- phase 2: persistent cooperative scan ----------
__global__ __launch_bounds__(512) void lstm_scan2(const _Float16* __restrict__ Zp,
                                                  const _Float16* __restrict__ WhP2,
                                                  const float* __restrict__ bv,
                                                  const int* __restrict__ resets,
                                                  const float* __restrict__ c0,
                                                  _Float16* __restrict__ hbuf,  // [2][B][H]
                                                  int* __restrict__ bar,
                                                  float* __restrict__ out) {
    const int n    = blockIdx.x;
    const int tid  = threadIdx.x;
    const int lane = tid & 63;
    const int w    = tid >> 6;                 // wave id = m-tile (16 batch rows)
    const int jbase = n * 8;

    __shared__ _Float16 WL[16384];             // 32KB weight slice
    __shared__ float    zl[128 * 33];          // z exchange, padded rows

    {   // weights: one-time linear copy to LDS
        const half8* src = (const half8*)(WhP2 + (size_t)n * 16384);
        half8* dst = (half8*)WL;
        for (int i = tid; i < 2048; i += 512) dst[i] = src[i];
    }

    const int b   = tid >> 2;                  // batch row this thread finalizes
    const int q   = tid & 3;
    const int jj0 = q * 2;                     // handles jj0, jj0+1

    float bia[4][2];
    #pragma unroll
    for (int g = 0; g < 4; ++g) {
        bia[g][0] = bv[g * 512 + jbase + jj0];
        bia[g][1] = bv[g * 512 + jbase + jj0 + 1];
    }

    float cc0 = c0[b * 512 + jbase + jj0];
    float cc1 = c0[b * 512 + jbase + jj0 + 1];
    float hh0 = 0.f, hh1 = 0.f;

    float* ys = out + 2 * (B_ * H_);

    const int arow = w * 16 + (lane & 15);
    // h row in 8B units: arow*128; column offset (lane>>4)*8 f16 = (lane>>4)*2 u64
    const int hq = arow * 128 + (lane >> 4) * 2;
    const int boff = ((lane >> 4) * 16 + (lane & 15)) * 8;

    __syncthreads();                           // WL ready

    for (int t = 0; t < T_; ++t) {
        const uint64_t* hsrc = (const uint64_t*)(hbuf + (size_t)(t & 1) * (B_ * H_)) + hq;

        // coherent h loads (MALL-served, no cache maintenance)
        half8 av[16];
        #pragma unroll
        for (int ks = 0; ks < 16; ++ks) {
            uint64_t lo = __hip_atomic_load(hsrc + ks * 8,     __ATOMIC_RELAXED, __HIP_MEMORY_SCOPE_AGENT);
            uint64_t hi = __hip_atomic_load(hsrc + ks * 8 + 1, __ATOMIC_RELAXED, __HIP_MEMORY_SCOPE_AGENT);
            union { uint64_t u[2]; half8 v; } cv;
            cv.u[0] = lo; cv.u[1] = hi;
            av[ks] = cv.v;
        }

        f32x4 acc0 = (f32x4){0.f,0.f,0.f,0.f}, acc1 = (f32x4){0.f,0.f,0.f,0.f};
        #pragma unroll
        for (int ks = 0; ks < 16; ++ks) {
            half8 b0 = *(const half8*)&WL[ks * 512 + boff];
            half8 b1 = *(const half8*)&WL[(16 + ks) * 512 + boff];
            acc0 = __builtin_amdgcn_mfma_f32_16x16x32_f16(av[ks], b0, acc0, 0, 0, 0);
            acc1 = __builtin_amdgcn_mfma_f32_16x16x32_f16(av[ks], b1, acc1, 0, 0, 0);
        }

        {   // scatter z to LDS (row-padded)
            const int r0 = w * 16 + (lane >> 4) * 4;
            const int cl = lane & 15;
            #pragma unroll
            for (int e = 0; e < 4; ++e) {
                zl[(r0 + e) * 33 + cl]      = acc0[e];
                zl[(r0 + e) * 33 + 16 + cl] = acc1[e];
            }
        }
        __syncthreads();

        // epilogue: gates for (b, jj0), (b, jj0+1)
        const int  rb  = resets[t * B_ + b];
        const float cm0 = rb ? 0.f : cc0;
        const float cm1 = rb ? 0.f : cc1;
        const _Float16* zp = Zp + (((size_t)t * NB + n) * 128 + b) * 32;
        float zt[4][2];
        #pragma unroll
        for (int g = 0; g < 4; ++g) {
            zt[g][0] = zl[b * 33 + g * 8 + jj0]     + bia[g][0] + (float)zp[g * 8 + jj0];
            zt[g][1] = zl[b * 33 + g * 8 + jj0 + 1] + bia[g][1] + (float)zp[g * 8 + jj0 + 1];
        }
        {
            float ig = 1.f / (1.f + __expf(-zt[0][0]));
            float fg = 1.f / (1.f + __expf(-zt[1][0]));
            float gg = 1.f - 2.f / (1.f + __expf(2.f * zt[2][0]));
            float og = 1.f / (1.f + __expf(-zt[3][0]));
            cc0 = fg * cm0 + ig * gg;
            hh0 = og * (1.f - 2.f / (1.f + __expf(2.f * cc0)));
        }
        {
            float ig = 1.f / (1.f + __expf(-zt[0][1]));
            float fg = 1.f / (1.f + __expf(-zt[1][1]));
            float gg = 1.f - 2.f / (1.f + __expf(2.f * zt[2][1]));
            float og = 1.f / (1.f + __expf(-zt[3][1]));
            cc1 = fg * cm1 + ig * gg;
            hh1 = og * (1.f - 2.f / (1.f + __expf(2.f * cc1)));
        }

        *(float2*)&ys[(size_t)(t * B_ + b) * H_ + jbase + jj0] = (float2){hh0, hh1};

        const int rn = (t + 1 < T_) ? resets[(t + 1) * B_ + b] : 0;
        union { unsigned int u; _Float16 h[2]; } hp;
        hp.h[0] = (_Float16)(rn ? 0.f : hh0);
        hp.h[1] = (_Float16)(rn ? 0.f : hh1);
        // coherent h store (write-through to MALL)
        __hip_atomic_store((unsigned int*)(hbuf + (size_t)((t + 1) & 1) * (B_ * H_) + b * 512 + jbase + jj0),
                           hp.u, __ATOMIC_RELAXED, __HIP_MEMORY_SCOPE_AGENT);

        __syncthreads();                       // drains vmcnt(0): h stores ack'd at MALL
        if (tid == 0) {
            __hip_atomic_fetch_add(bar, 1, __ATOMIC_RELAXED, __HIP_MEMORY_SCOPE_AGENT);
            const int target = NB * (t + 1);
            while (__hip_atomic_load(bar, __ATOMIC_RELAXED, __HIP_MEMORY_SCOPE_AGENT) < target)
                __builtin_amdgcn_s_sleep(4);
        }
        __syncthreads();                       // release block; h_{t+1} visible
    }

    // final outputs: c_T and raw h_T
    *(float2*)&out[b * 512 + jbase + jj0]            = (float2){cc0, cc1};
    *(float2*)&out[B_ * H_ + b * 512 + jbase + jj0]  = (float2){hh0, hh1};
}

// ---------- fallback: all-f32 fused (used only if workspace too small) ----------
__global__ __launch_bounds__(512) void lstm_fb(const float* __restrict__ ins,
                                               const int* __restrict__ resets,
                                               const float* __restrict__ c0,
                                               const float* __restrict__ h0,
                                               const float* __restrict__ Wi,
                                               const float* __restrict__ Wh,
                                               const float* __restrict__ bv,
                                               float* __restrict__ out) {
    const int b = blockIdx.x;
    const int j = threadIdx.x;
    __shared__ float hs[H_];
    __shared__ float xs[D_];

    float c = c0[b * H_ + j];
    hs[j] = h0[b * H_ + j];
    const float b0 = bv[j], b1 = bv[H_ + j], b2 = bv[2 * H_ + j], b3 = bv[3 * H_ + j];
    float* ys = out + 2 * B_ * H_;

    for (int t = 0; t < T_; ++t) {
        __syncthreads();
        xs[j] = ins[((size_t)(t * B_ + b)) * D_ + j];
        __syncthreads();
        const bool rst = resets[t * B_ + b] != 0;
        float z0 = b0, z1 = b1, z2 = b2, z3 = b3;
        for (int k = 0; k < D_; ++k) {
            float xk = xs[k];
            z0 += xk * Wi[(size_t)k * N4H + j];
            z1 += xk * Wi[(size_t)k * N4H + H_ + j];
            z2 += xk * Wi[(size_t)k * N4H + 2 * H_ + j];
            z3 += xk * Wi[(size_t)k * N4H + 3 * H_ + j];
        }
        float c_use = rst ? 0.f : c;
        if (!rst) {
            for (int k = 0; k < H_; ++k) {
                float hk = hs[k];
                z0 += hk * Wh[(size_t)k * N4H + j];
                z1 += hk * Wh[(size_t)k * N4H + H_ + j];
                z2 += hk * Wh[(size_t)k * N4H + 2 * H_ + j];
                z3 += hk * Wh[(size_t)k * N4H + 3 * H_ + j];
            }
        }
        float ig = 1.f / (1.f + __expf(-z0));
        float fg = 1.f / (1.f + __expf(-z1));
        float gg = 1.f - 2.f / (1.f + __expf(2.f * z2));
        float og = 1.f / (1.f + __expf(-z3));
        c = fg * c_use + ig * gg;
        float tc = 1.f - 2.f / (1.f + __expf(2.f * c));
        float h = og * tc;
        __syncthreads();
        hs[j] = h;
        ys[((size_t)(t * B_ + b)) * H_ + j] = h;
    }
    out[b * H_ + j] = c;
    out[B_ * H_ + b * H_ + j] = hs[j];
}

extern "C" void kernel_launch(void* const* d_in, const int* in_sizes, int n_in,
                              void* d_out, int out_size, void* d_ws, size_t ws_size,
                              hipStream_t stream) {
    const float* ins    = (const float*)d_in[0];
    const int*   resets = (const int*)d_in[1];
    const float* c0     = (const float*)d_in[2];
    const float* h0     = (const float*)d_in[3];
    const float* Wi     = (const float*)d_in[4];
    const float* Wh     = (const float*)d_in[5];
    const float* bv     = (const float*)d_in[6];
    float*       out    = (float*)d_out;

    const size_t offXH  = 0;                                   // ins f16 (64MB); reused later
    const size_t offWiT = offXH  + (size_t)T_ * B_ * D_ * 2;
    const size_t offWhP = offWiT + (size_t)D_ * N4H * 2;
    const size_t offZ   = offWhP + (size_t)H_ * N4H * 2;
    const size_t need   = offZ   + (size_t)T_ * B_ * N4H * 2;

    if (ws_size >= need) {
        _Float16* XH   = (_Float16*)((char*)d_ws + offXH);
        _Float16* WiT  = (_Float16*)((char*)d_ws + offWiT);
        _Float16* WhP2 = (_Float16*)((char*)d_ws + offWhP);
        _Float16* Zp   = (_Float16*)((char*)d_ws + offZ);
        // hbuf + bar reuse the XH region (XH fully consumed by gemm before init_h)
        _Float16* hbuf = (_Float16*)((char*)d_ws + offXH);               // 2*B*H f16 = 256KB
        int*      bar  = (int*)((char*)d_ws + offXH + 2 * B_ * H_ * 2);

        cvt_ins<<<(T_ * B_ * D_ / 4) / 256, 256, 0, stream>>>(ins, XH);
        cvt_wi <<<(D_ * N4H) / 256,         256, 0, stream>>>(Wi, WiT);
        cvt_wh2<<<(H_ * N4H) / 256,         256, 0, stream>>>(Wh, WhP2);
        gemm_xwi<<<dim3(T_ * B_ / 128, N4H / 128), 256, 0, stream>>>(XH, WiT, Zp);
        init_h<<<B_ * H_ / 512, 512, 0, stream>>>(h0, resets, hbuf, bar);
        lstm_scan2<<<NB, 512, 0, stream>>>(Zp, WhP2, bv, resets, c0, hbuf, bar, out);
    } else {
        lstm_fb<<<B_, H_, 0, stream>>>(ins, resets, c0, h0, Wi, Wh, bv, out);
    }
}

// Round 5
// 2938.197 us; speedup vs baseline: 2.0371x; 1.9799x over previous
//
#include <hip/hip_runtime.h>

#define T_  512
#define B_  128
#define D_  512
#define H_  512
#define N4H 2048
#define NB  64          // scan blocks; each owns 8 h-columns

typedef _Float16 half8  __attribute__((ext_vector_type(8)));
typedef _Float16 half4v __attribute__((ext_vector_type(4)));
typedef float    f32x4  __attribute__((ext_vector_type(4)));

// ---------- converts ----------
__global__ void cvt_ins(const float* __restrict__ in, _Float16* __restrict__ out) {
    int i = blockIdx.x * 256 + threadIdx.x;
    float4 v = ((const float4*)in)[i];
    half4v o;
    o[0] = (_Float16)v.x; o[1] = (_Float16)v.y;
    o[2] = (_Float16)v.z; o[3] = (_Float16)v.w;
    ((half4v*)out)[i] = o;
}

__global__ void cvt_wi(const float* __restrict__ Wi, _Float16* __restrict__ WiT) {
    int i = blockIdx.x * 256 + threadIdx.x;            // over 512*2048
    int k = i >> 11, n = i & 2047;
    WiT[n * D_ + k] = (_Float16)Wi[i];                 // transpose: [N][K]
}

// Pack Wh into per-scan-block LDS-ready layout (see R3 notes).
__global__ void cvt_wh2(const float* __restrict__ Wh, _Float16* __restrict__ WhP2) {
    int i = blockIdx.x * 256 + threadIdx.x;            // over 512*2048 (coalesced src)
    int k = i >> 11, gcol = i & 2047;
    int g = gcol >> 9, j = gcol & 511;
    int n = j >> 3, jj = j & 7;
    int sc = g * 8 + jj;
    int nt = sc >> 4, col = sc & 15;
    int ks = k >> 5, kc = (k >> 3) & 3, e = k & 7;
    int idx = (nt * 16 + ks) * 512 + (kc * 16 + col) * 8 + e;
    WhP2[(size_t)n * 16384 + idx] = (_Float16)Wh[i];
}

// hbuf[0] = resets[0]-masked h0 in OWNER-CONTIGUOUS layout [64][128][8]; zero flags
__global__ void init_h(const float* __restrict__ h0, const int* __restrict__ resets,
                       _Float16* __restrict__ hbuf, int* __restrict__ flags) {
    int i = blockIdx.x * 512 + threadIdx.x;            // over B*H
    int b = i >> 9, j = i & 511;
    float v = resets[b] ? 0.f : h0[i];
    hbuf[(size_t)(j >> 3) * 1024 + b * 8 + (j & 7)] = (_Float16)v;
    if (i < 64 * 32) flags[i] = 0;
}

// ---------- phase 1: Z = X @ WiT^T, PERMUTED so scan thread reads one 16B ----------
__global__ __launch_bounds__(256) void gemm_xwi(const _Float16* __restrict__ X,
                                                const _Float16* __restrict__ WT,
                                                _Float16* __restrict__ Zp) {
    __shared__ _Float16 As[128 * 32];
    __shared__ _Float16 Bs[128 * 32];
    const int tid  = threadIdx.x;
    const int lane = tid & 63;
    const int wid  = tid >> 6;
    const int wm   = wid >> 1, wn = wid & 1;
    const int bm   = blockIdx.x, bn = blockIdx.y;

    f32x4 acc[4][4];
    #pragma unroll
    for (int m = 0; m < 4; ++m)
        #pragma unroll
        for (int n = 0; n < 4; ++n)
            acc[m][n] = (f32x4){0.f, 0.f, 0.f, 0.f};

    const _Float16* Xb = X  + (size_t)bm * 128 * D_;
    const _Float16* Wb = WT + (size_t)bn * 128 * D_;

    for (int kt = 0; kt < D_ / 32; ++kt) {
        if (kt) __syncthreads();
        #pragma unroll
        for (int s = 0; s < 2; ++s) {
            int idx = tid + s * 256;
            int row = idx >> 2, cg = idx & 3;
            *(half8*)&As[idx * 8] = *(const half8*)&Xb[row * D_ + kt * 32 + cg * 8];
            *(half8*)&Bs[idx * 8] = *(const half8*)&Wb[row * D_ + kt * 32 + cg * 8];
        }
        __syncthreads();
        half8 a[4], b[4];
        #pragma unroll
        for (int m = 0; m < 4; ++m)
            a[m] = *(const half8*)&As[(wm * 64 + m * 16 + (lane & 15)) * 32 + (lane >> 4) * 8];
        #pragma unroll
        for (int n = 0; n < 4; ++n)
            b[n] = *(const half8*)&Bs[(wn * 64 + n * 16 + (lane & 15)) * 32 + (lane >> 4) * 8];
        #pragma unroll
        for (int m = 0; m < 4; ++m)
            #pragma unroll
            for (int n = 0; n < 4; ++n)
                acc[m][n] = __builtin_amdgcn_mfma_f32_16x16x32_f16(a[m], b[n], acc[m][n], 0, 0, 0);
    }

    const int row0 = bm * 128 + wm * 64;
    const int col0 = bn * 128 + wn * 64;
    #pragma unroll
    for (int m = 0; m < 4; ++m)
        #pragma unroll
        for (int n = 0; n < 4; ++n)
            #pragma unroll
            for (int e = 0; e < 4; ++e) {
                int r = row0 + m * 16 + (lane >> 4) * 4 + e;   // t*B + b
                int c = col0 + n * 16 + (lane & 15);           // gate col
                int t = r >> 7, bb = r & 127;
                int g = c >> 9, j = c & 511;
                int nb = j >> 3, jj = j & 7;
                int q = jj >> 1, e2 = jj & 1;
                // Zp[t][nb][bb][q][g*2+e2]
                Zp[((((size_t)t * NB + nb) * 128 + bb) * 4 + q) * 8 + g * 2 + e2] = (_Float16)acc[m][n][e];
            }
}

// ---------- phase 2: persistent cooperative scan ----------
__global__ __launch_bounds__(512) void lstm_scan2(const _Float16* __restrict__ Zp,
                                                  const _Float16* __restrict__ WhP2,
                                                  const float* __restrict__ bv,
                                                  const int* __restrict__ resets,
                                                  const float* __restrict__ c0,
                                                  _Float16* __restrict__ hbuf,  // [2][64][128][8]
                                                  int* __restrict__ flags,      // [64] stride 32
                                                  float* __restrict__ out) {
    const int n    = blockIdx.x;
    const int tid  = threadIdx.x;
    const int lane = tid & 63;
    const int w    = tid >> 6;                 // wave id = m-tile (16 batch rows)
    const int jbase = n * 8;

    __shared__ _Float16 WL[16384];             // 32KB weight slice
    __shared__ float    zl[128 * 33];          // z exchange, padded rows

    {   // weights: one-time linear copy to LDS
        const half8* src = (const half8*)(WhP2 + (size_t)n * 16384);
        half8* dst = (half8*)WL;
        for (int i = tid; i < 2048; i += 512) dst[i] = src[i];
    }

    const int b   = tid >> 2;                  // batch row this thread finalizes
    const int q   = tid & 3;
    const int jj0 = q * 2;                     // handles jj0, jj0+1

    float bia[4][2];
    #pragma unroll
    for (int g = 0; g < 4; ++g) {
        bia[g][0] = bv[g * 512 + jbase + jj0];
        bia[g][1] = bv[g * 512 + jbase + jj0 + 1];
    }

    float cc0 = c0[b * 512 + jbase + jj0];
    float cc1 = c0[b * 512 + jbase + jj0 + 1];
    float hh0 = 0.f, hh1 = 0.f;

    float* ys = out + 2 * (B_ * H_);

    const int arow = w * 16 + (lane & 15);
    const int kg   = lane >> 4;                // 0..3 (k col-group)
    const int boff = (kg * 16 + (lane & 15)) * 8;

    // prologue prefetches
    half8 zp_cur = *(const half8*)(Zp + (((size_t)0 * NB + n) * 128 + b) * 32 + q * 8);
    int   r_cur  = resets[b];

    __syncthreads();                           // WL ready

    for (int t = 0; t < T_; ++t) {
        const int tn = (t + 1 < T_) ? (t + 1) : (T_ - 1);
        const int r_next = resets[tn * B_ + b];          // early prefetch

        // --- h loads (coherent, owner-contiguous layout) + MFMA ---
        const uint64_t* hc = (const uint64_t*)(hbuf + (size_t)(t & 1) * (NB * 128 * 8));
        half8 av[16];
        #pragma unroll
        for (int ks = 0; ks < 16; ++ks) {
            const uint64_t* p = hc + (size_t)(ks * 4 + kg) * 256 + arow * 2;
            uint64_t lo = __hip_atomic_load(p,     __ATOMIC_RELAXED, __HIP_MEMORY_SCOPE_AGENT);
            uint64_t hi = __hip_atomic_load(p + 1, __ATOMIC_RELAXED, __HIP_MEMORY_SCOPE_AGENT);
            union { uint64_t u[2]; half8 v; } cv;
            cv.u[0] = lo; cv.u[1] = hi;
            av[ks] = cv.v;
        }

        f32x4 acc0 = (f32x4){0.f,0.f,0.f,0.f}, acc1 = (f32x4){0.f,0.f,0.f,0.f};
        #pragma unroll
        for (int ks = 0; ks < 16; ++ks) {
            half8 b0 = *(const half8*)&WL[ks * 512 + boff];
            half8 b1 = *(const half8*)&WL[(16 + ks) * 512 + boff];
            acc0 = __builtin_amdgcn_mfma_f32_16x16x32_f16(av[ks], b0, acc0, 0, 0, 0);
            acc1 = __builtin_amdgcn_mfma_f32_16x16x32_f16(av[ks], b1, acc1, 0, 0, 0);
        }

        {   // scatter z to LDS (row-padded)
            const int r0 = w * 16 + kg * 4;
            const int cl = lane & 15;
            #pragma unroll
            for (int e = 0; e < 4; ++e) {
                zl[(r0 + e) * 33 + cl]      = acc0[e];
                zl[(r0 + e) * 33 + 16 + cl] = acc1[e];
            }
        }
        __syncthreads();

        // --- gates for (b, jj0), (b, jj0+1) using prefetched zp_cur ---
        const float cm0 = r_cur ? 0.f : cc0;
        const float cm1 = r_cur ? 0.f : cc1;
        float zt[4][2];
        #pragma unroll
        for (int g = 0; g < 4; ++g) {
            zt[g][0] = zl[b * 33 + g * 8 + jj0]     + bia[g][0] + (float)zp_cur[g * 2];
            zt[g][1] = zl[b * 33 + g * 8 + jj0 + 1] + bia[g][1] + (float)zp_cur[g * 2 + 1];
        }
        {
            float ig = 1.f / (1.f + __expf(-zt[0][0]));
            float fg = 1.f / (1.f + __expf(-zt[1][0]));
            float gg = 1.f - 2.f / (1.f + __expf(2.f * zt[2][0]));
            float og = 1.f / (1.f + __expf(-zt[3][0]));
            cc0 = fg * cm0 + ig * gg;
            hh0 = og * (1.f - 2.f / (1.f + __expf(2.f * cc0)));
        }
        {
            float ig = 1.f / (1.f + __expf(-zt[0][1]));
            float fg = 1.f / (1.f + __expf(-zt[1][1]));
            float gg = 1.f - 2.f / (1.f + __expf(2.f * zt[2][1]));
            float og = 1.f / (1.f + __expf(-zt[3][1]));
            cc1 = fg * cm1 + ig * gg;
            hh1 = og * (1.f - 2.f / (1.f + __expf(2.f * cc1)));
        }

        // --- h store FIRST (coherent, coalesced 2KB per block), masked by resets[t+1] ---
        union { unsigned int u; _Float16 h[2]; } hp;
        hp.h[0] = (_Float16)(r_next ? 0.f : hh0);
        hp.h[1] = (_Float16)(r_next ? 0.f : hh1);
        __hip_atomic_store((unsigned int*)(hbuf + (size_t)((t + 1) & 1) * (NB * 128 * 8)) + n * 512 + b * 4 + q,
                           hp.u, __ATOMIC_RELAXED, __HIP_MEMORY_SCOPE_AGENT);

        // --- ys store + next-step Zp prefetch (both drain under the same barrier) ---
        *(float2*)&ys[(size_t)(t * B_ + b) * H_ + jbase + jj0] = (float2){hh0, hh1};
        half8 zp_next = *(const half8*)(Zp + (((size_t)tn * NB + n) * 128 + b) * 32 + q * 8);

        __syncthreads();                       // vmcnt(0): h stores ack'd, prefetch landed
        if (tid < 64) {                        // wave 0: flag-array barrier
            __hip_atomic_store(&flags[n * 32], t + 1, __ATOMIC_RELAXED, __HIP_MEMORY_SCOPE_AGENT);
            int v = __hip_atomic_load(&flags[lane * 32], __ATOMIC_RELAXED, __HIP_MEMORY_SCOPE_AGENT);
            while (!__all(v >= t + 1)) {
                __builtin_amdgcn_s_sleep(1);
                v = __hip_atomic_load(&flags[lane * 32], __ATOMIC_RELAXED, __HIP_MEMORY_SCOPE_AGENT);
            }
        }
        __syncthreads();                       // release block; h_{t+1} visible

        zp_cur = zp_next;
        r_cur  = r_next;
    }

    // final outputs: c_T and raw h_T
    *(float2*)&out[b * 512 + jbase + jj0]            = (float2){cc0, cc1};
    *(float2*)&out[B_ * H_ + b * 512 + jbase + jj0]  = (float2){hh0, hh1};
}

// ---------- fallback: all-f32 fused (used only if workspace too small) ----------
__global__ __launch_bounds__(512) void lstm_fb(const float* __restrict__ ins,
                                               const int* __restrict__ resets,
                                               const float* __restrict__ c0,
                                               const float* __restrict__ h0,
                                               const float* __restrict__ Wi,
                                               const float* __restrict__ Wh,
                                               const float* __restrict__ bv,
                                               float* __restrict__ out) {
    const int b = blockIdx.x;
    const int j = threadIdx.x;
    __shared__ float hs[H_];
    __shared__ float xs[D_];

    float c = c0[b * H_ + j];
    hs[j] = h0[b * H_ + j];
    const float b0 = bv[j], b1 = bv[H_ + j], b2 = bv[2 * H_ + j], b3 = bv[3 * H_ + j];
    float* ys = out + 2 * B_ * H_;

    for (int t = 0; t < T_; ++t) {
        __syncthreads();
        xs[j] = ins[((size_t)(t * B_ + b)) * D_ + j];
        __syncthreads();
        const bool rst = resets[t * B_ + b] != 0;
        float z0 = b0, z1 = b1, z2 = b2, z3 = b3;
        for (int k = 0; k < D_; ++k) {
            float xk = xs[k];
            z0 += xk * Wi[(size_t)k * N4H + j];
            z1 += xk * Wi[(size_t)k * N4H + H_ + j];
            z2 += xk * Wi[(size_t)k * N4H + 2 * H_ + j];
            z3 += xk * Wi[(size_t)k * N4H + 3 * H_ + j];
        }
        float c_use = rst ? 0.f : c;
        if (!rst) {
            for (int k = 0; k < H_; ++k) {
                float hk = hs[k];
                z0 += hk * Wh[(size_t)k * N4H + j];
                z1 += hk * Wh[(size_t)k * N4H + H_ + j];
                z2 += hk * Wh[(size_t)k * N4H + 2 * H_ + j];
                z3 += hk * Wh[(size_t)k * N4H + 3 * H_ + j];
            }
        }
        float ig = 1.f / (1.f + __expf(-z0));
        float fg = 1.f / (1.f + __expf(-z1));
        float gg = 1.f - 2.f / (1.f + __expf(2.f * z2));
        float og = 1.f / (1.f + __expf(-z3));
        c = fg * c_use + ig * gg;
        float tc = 1.f - 2.f / (1.f + __expf(2.f * c));
        float h = og * tc;
        __syncthreads();
        hs[j] = h;
        ys[((size_t)(t * B_ + b)) * H_ + j] = h;
    }
    out[b * H_ + j] = c;
    out[B_ * H_ + b * H_ + j] = hs[j];
}

extern "C" void kernel_launch(void* const* d_in, const int* in_sizes, int n_in,
                              void* d_out, int out_size, void* d_ws, size_t ws_size,
                              hipStream_t stream) {
    const float* ins    = (const float*)d_in[0];
    const int*   resets = (const int*)d_in[1];
    const float* c0     = (const float*)d_in[2];
    const float* h0     = (const float*)d_in[3];
    const float* Wi     = (const float*)d_in[4];
    const float* Wh     = (const float*)d_in[5];
    const float* bv     = (const float*)d_in[6];
    float*       out    = (float*)d_out;

    const size_t offXH  = 0;                                   // ins f16 (64MB); reused later
    const size_t offWiT = offXH  + (size_t)T_ * B_ * D_ * 2;
    const size_t offWhP = offWiT + (size_t)D_ * N4H * 2;
    const size_t offZ   = offWhP + (size_t)H_ * N4H * 2;
    const size_t need   = offZ   + (size_t)T_ * B_ * N4H * 2;

    if (ws_size >= need) {
        _Float16* XH    = (_Float16*)((char*)d_ws + offXH);
        _Float16* WiT   = (_Float16*)((char*)d_ws + offWiT);
        _Float16* WhP2  = (_Float16*)((char*)d_ws + offWhP);
        _Float16* Zp    = (_Float16*)((char*)d_ws + offZ);
        // hbuf + flags reuse the XH region (XH fully consumed by gemm before init_h)
        _Float16* hbuf  = (_Float16*)((char*)d_ws + offXH);              // 2*64*128*8 f16 = 256KB
        int*      flags = (int*)((char*)d_ws + offXH + 2 * NB * 128 * 8 * 2);

        cvt_ins<<<(T_ * B_ * D_ / 4) / 256, 256, 0, stream>>>(ins, XH);
        cvt_wi <<<(D_ * N4H) / 256,         256, 0, stream>>>(Wi, WiT);
        cvt_wh2<<<(H_ * N4H) / 256,         256, 0, stream>>>(Wh, WhP2);
        gemm_xwi<<<dim3(T_ * B_ / 128, N4H / 128), 256, 0, stream>>>(XH, WiT, Zp);
        init_h<<<B_ * H_ / 512, 512, 0, stream>>>(h0, resets, hbuf, flags);
        lstm_scan2<<<NB, 512, 0, stream>>>(Zp, WhP2, bv, resets, c0, hbuf, flags, out);
    } else {
        lstm_fb<<<B_, H_, 0, stream>>>(ins, resets, c0, h0, Wi, Wh, bv, out);
    }
}